// Round 2
// baseline (1739.755 us; speedup 1.0000x reference)
//
#include <hip/hip_runtime.h>
#include <stdint.h>

// ---------------------------------------------------------------------------
// FloydBlock2: global-norm -> QKV GEMM -> pivotal attention (row+col streams)
// B=4, N=128, C=512, H=8, D=64, SCALE=6.25
// Dtype-adaptive: runtime probe decides fp32 vs bf16 I/O. Internally the GEMM
// uses hi/lo bf16 splits so fp32-mode accuracy is ~2^-17 on qkv.
// ---------------------------------------------------------------------------

typedef __attribute__((ext_vector_type(8))) short s8v;   // 8 x bf16 (4 VGPRs)
typedef __attribute__((ext_vector_type(4))) float f4v;   // MFMA accumulator

#define MFMA(a, b, c) __builtin_amdgcn_mfma_f32_16x16x32_bf16((a), (b), (c), 0, 0, 0)

__device__ __forceinline__ float bf2f(unsigned short u) {
  union { unsigned int i; float f; } v; v.i = ((unsigned int)u) << 16; return v.f;
}
__device__ __forceinline__ unsigned short f2bf(float f) {
  union { float f; unsigned int i; } v; v.f = f;
  unsigned int i = v.i;
  return (unsigned short)((i + 0x7fffu + ((i >> 16) & 1u)) >> 16);  // RNE
}

// global -> LDS direct copy, 16B per lane. LDS dest must be wave-uniform+lane*16.
__device__ __forceinline__ void async_copy16(const void* g, void* l) {
  __builtin_amdgcn_global_load_lds(
      (const __attribute__((address_space(1))) unsigned int*)(uintptr_t)g,
      (__attribute__((address_space(3))) unsigned int*)(uintptr_t)l,
      16, 0, 0);
}

// ---------------------------------------------------------------------------
// 0) dtype probe: interpret first 4096 ushorts as bf16; fp32 data has random
//    low-half exponents -> |v|>1e4 or NaN with prob ~1. bf16 N(0,1) never.
// ---------------------------------------------------------------------------
__global__ __launch_bounds__(256) void k_probe(const unsigned short* __restrict__ x,
                                               int* __restrict__ flag) {
  uint4 v = ((const uint4*)x)[threadIdx.x];
  unsigned int uu[4] = {v.x, v.y, v.z, v.w};
  int bad = 0;
#pragma unroll
  for (int u = 0; u < 4; ++u) {
    float a = bf2f((unsigned short)(uu[u] & 0xffffu));
    float b = bf2f((unsigned short)(uu[u] >> 16));
    if (!(fabsf(a) <= 1e4f)) bad = 1;   // catches NaN too
    if (!(fabsf(b) <= 1e4f)) bad = 1;
  }
  if (bad) atomicOr(flag, 1);
}

// ---------------------------------------------------------------------------
// 1) Global sum / sumsq over raw x (33.55M elements, dtype-branched)
// ---------------------------------------------------------------------------
__global__ __launch_bounds__(256) void k_red(const void* __restrict__ xraw,
                                             const int* __restrict__ flag,
                                             double* __restrict__ dstats) {
  __shared__ float red[8];
  const int fm = flag[0];
  int t = threadIdx.x;
  size_t gid = (size_t)blockIdx.x * 256 + t;
  float s = 0.f, ss = 0.f;
  if (fm) {
    const float4* pf = (const float4*)xraw;
#pragma unroll 4
    for (int it = 0; it < 32; ++it) {
      size_t idx = gid + (size_t)it * 131072;
      float4 u1 = pf[2 * idx], u2 = pf[2 * idx + 1];
      float vals[8] = {u1.x, u1.y, u1.z, u1.w, u2.x, u2.y, u2.z, u2.w};
#pragma unroll
      for (int u = 0; u < 8; ++u) { s += vals[u]; ss += vals[u] * vals[u]; }
    }
  } else {
    const uint4* p = (const uint4*)xraw;
#pragma unroll 4
    for (int it = 0; it < 32; ++it) {
      uint4 v = p[gid + (size_t)it * 131072];
      unsigned int uu[4] = {v.x, v.y, v.z, v.w};
#pragma unroll
      for (int u = 0; u < 4; ++u) {
        float a = bf2f((unsigned short)(uu[u] & 0xffffu));
        float b = bf2f((unsigned short)(uu[u] >> 16));
        s += a + b;
        ss += a * a + b * b;
      }
    }
  }
#pragma unroll
  for (int d = 32; d >= 1; d >>= 1) {
    s += __shfl_down(s, d);
    ss += __shfl_down(ss, d);
  }
  int lane = t & 63, wave = t >> 6;
  if (lane == 0) { red[wave] = s; red[4 + wave] = ss; }
  __syncthreads();
  if (t == 0) {
    atomicAdd(&dstats[0], (double)(red[0] + red[1] + red[2] + red[3]));
    atomicAdd(&dstats[1], (double)(red[4] + red[5] + red[6] + red[7]));
  }
}

__global__ void k_stats(const double* __restrict__ dstats, float* __restrict__ fstats) {
  double M = 33554432.0;
  double mean = dstats[0] / M;
  double var = (dstats[1] - dstats[0] * dstats[0] / M) / (M - 1.0);  // ddof=1
  double istd = 1.0 / sqrt(var);
  fstats[0] = (float)istd;            // a: multiply accumulator
  fstats[1] = (float)(-mean * istd);  // b: times colsum(w)
}

// colsum[c] = sum_r w[r][c]
__global__ __launch_bounds__(256) void k_colsum(const void* __restrict__ wraw,
                                                const int* __restrict__ flag,
                                                float* __restrict__ colsum) {
  const int fm = flag[0];
  int c = blockIdx.x * 256 + threadIdx.x;
  if (c >= 2560) return;
  float s = 0.f;
  if (fm) {
    const float* w = (const float*)wraw;
    for (int r = 0; r < 512; ++r) s += w[(size_t)r * 2560 + c];
  } else {
    const unsigned short* w = (const unsigned short*)wraw;
    for (int r = 0; r < 512; ++r) s += bf2f(w[(size_t)r * 2560 + c]);
  }
  colsum[c] = s;
}

// wT hi/lo [n][k] = split(w[k][n])  (2560 x 512)
__global__ __launch_bounds__(256) void k_wt(const void* __restrict__ wraw,
                                            const int* __restrict__ flag,
                                            unsigned short* __restrict__ wThi,
                                            unsigned short* __restrict__ wTlo) {
  __shared__ float tile[64][65];
  const int fm = flag[0];
  int n0 = blockIdx.x * 64, r0 = blockIdx.y * 64;
#pragma unroll
  for (int rep = 0; rep < 16; ++rep) {
    int idx = rep * 256 + threadIdx.x;
    int r = idx >> 6, n = idx & 63;
    float v;
    if (fm) v = ((const float*)wraw)[(size_t)(r0 + r) * 2560 + n0 + n];
    else    v = bf2f(((const unsigned short*)wraw)[(size_t)(r0 + r) * 2560 + n0 + n]);
    tile[r][n] = v;
  }
  __syncthreads();
#pragma unroll
  for (int rep = 0; rep < 16; ++rep) {
    int idx = rep * 256 + threadIdx.x;
    int n = idx >> 6, r = idx & 63;
    float v = tile[r][n];
    unsigned short hi = f2bf(v);
    size_t o = (size_t)(n0 + n) * 512 + r0 + r;
    wThi[o] = hi;
    wTlo[o] = f2bf(v - bf2f(hi));
  }
}

// per-b slice conversion: x[b] -> xhi/xlo bf16 [16384][512]
__global__ __launch_bounds__(256) void k_convx(const void* __restrict__ xraw,
                                               const int* __restrict__ flag,
                                               unsigned short* __restrict__ xhi,
                                               unsigned short* __restrict__ xlo,
                                               int b) {
  const int fm = flag[0];
  size_t e0 = ((size_t)blockIdx.x * 256 + threadIdx.x) * 8;   // < 8,388,608
  size_t g0 = (size_t)b * 8388608 + e0;
  float vals[8];
  if (fm) {
    const float4* pf = (const float4*)xraw;
    float4 u1 = pf[g0 / 4], u2 = pf[g0 / 4 + 1];
    vals[0] = u1.x; vals[1] = u1.y; vals[2] = u1.z; vals[3] = u1.w;
    vals[4] = u2.x; vals[5] = u2.y; vals[6] = u2.z; vals[7] = u2.w;
  } else {
    uint4 v = ((const uint4*)xraw)[g0 / 8];
    unsigned int uu[4] = {v.x, v.y, v.z, v.w};
#pragma unroll
    for (int u = 0; u < 4; ++u) {
      vals[2 * u] = bf2f((unsigned short)(uu[u] & 0xffffu));
      vals[2 * u + 1] = bf2f((unsigned short)(uu[u] >> 16));
    }
  }
  unsigned short h[8], l[8];
#pragma unroll
  for (int u = 0; u < 8; ++u) {
    h[u] = f2bf(vals[u]);
    l[u] = f2bf(vals[u] - bf2f(h[u]));
  }
  *(uint4*)(xhi + e0) = *(const uint4*)h;
  *(uint4*)(xlo + e0) = *(const uint4*)l;
}

// ---------------------------------------------------------------------------
// 2) QKV GEMM, 128x128x64 tiles, hi/lo 3-term MFMA in fp32 mode.
//    Epilogue: val = a*acc + b*colsum[wcol]; scatter into head layouts.
//    q   [hl][i][j][d]   k1 [hl][i][k][d]   k2t [hl][j][k][d]
//    v1T [hl][i][d][k]   v2T [hl][j][d][k]
// ---------------------------------------------------------------------------
__global__ __launch_bounds__(256) void k_gemm(
    const unsigned short* __restrict__ xhi, const unsigned short* __restrict__ xlo,
    const unsigned short* __restrict__ wThi, const unsigned short* __restrict__ wTlo,
    const float* __restrict__ colsum, const float* __restrict__ fstats,
    const int* __restrict__ flag,
    unsigned short* __restrict__ qhi, unsigned short* __restrict__ qlo,
    unsigned short* __restrict__ k1hi, unsigned short* __restrict__ k1lo,
    unsigned short* __restrict__ k2hi, unsigned short* __restrict__ k2lo,
    unsigned short* __restrict__ v1T, unsigned short* __restrict__ v2T,
    int h0, int hcShift) {
  __shared__ __align__(16) unsigned short Ash[128 * 64];
  __shared__ __align__(16) unsigned short Asl[128 * 64];
  __shared__ __align__(16) unsigned short Bsh[128 * 64];
  __shared__ __align__(16) unsigned short Bsl[128 * 64];
  const int fm = flag[0];
  const int t = threadIdx.x;
  const int m0 = blockIdx.x * 128;
  const int n0 = blockIdx.y * 128;
  const int hcMask = (1 << hcShift) - 1;

  const int lane = t & 63, wave = t >> 6;
  const int wm = (wave & 1) * 64, wn = (wave >> 1) * 64;
  const int l16 = lane & 15, q4 = lane >> 4;
  const int srow = t >> 3;          // staging row 0..31
  const int scol = (t & 7) * 8;     // staging col (elements)

  const float af = fstats[0], bfc = fstats[1];
  const unsigned short* xh = xhi + (size_t)m0 * 512;
  const unsigned short* xl = xlo + (size_t)m0 * 512;

  f4v acc[4][4];
#pragma unroll
  for (int a = 0; a < 4; ++a)
#pragma unroll
    for (int c = 0; c < 4; ++c) acc[a][c] = (f4v)0.f;

  for (int k0 = 0; k0 < 512; k0 += 64) {
#pragma unroll
    for (int r = 0; r < 4; ++r) {
      int row = r * 32 + srow;
      async_copy16(xh + (size_t)row * 512 + k0 + scol, (char*)Ash + (r * 256 + t) * 16);
    }
#pragma unroll
    for (int r = 0; r < 4; ++r) {
      int row = r * 32 + srow;
      int ncol = n0 + row;
      int g = ncol >> hcShift, rem = ncol & hcMask;
      int wcol = (g << 9) + ((h0 + (rem >> 6)) << 6) + (rem & 63);
      async_copy16(wThi + (size_t)wcol * 512 + k0 + scol, (char*)Bsh + (r * 256 + t) * 16);
    }
    if (fm) {
#pragma unroll
      for (int r = 0; r < 4; ++r) {
        int row = r * 32 + srow;
        async_copy16(xl + (size_t)row * 512 + k0 + scol, (char*)Asl + (r * 256 + t) * 16);
      }
#pragma unroll
      for (int r = 0; r < 4; ++r) {
        int row = r * 32 + srow;
        int ncol = n0 + row;
        int g = ncol >> hcShift, rem = ncol & hcMask;
        int wcol = (g << 9) + ((h0 + (rem >> 6)) << 6) + (rem & 63);
        async_copy16(wTlo + (size_t)wcol * 512 + k0 + scol, (char*)Bsl + (r * 256 + t) * 16);
      }
    }
    __syncthreads();
#pragma unroll
    for (int kc = 0; kc < 2; ++kc) {
      s8v ah[4], bh[4];
#pragma unroll
      for (int jt = 0; jt < 4; ++jt)
        ah[jt] = *(const s8v*)&Ash[(wm + jt * 16 + l16) * 64 + kc * 32 + q4 * 8];
#pragma unroll
      for (int nt = 0; nt < 4; ++nt)
        bh[nt] = *(const s8v*)&Bsh[(wn + nt * 16 + l16) * 64 + kc * 32 + q4 * 8];
      if (fm) {
        s8v al[4], bl[4];
#pragma unroll
        for (int jt = 0; jt < 4; ++jt)
          al[jt] = *(const s8v*)&Asl[(wm + jt * 16 + l16) * 64 + kc * 32 + q4 * 8];
#pragma unroll
        for (int nt = 0; nt < 4; ++nt)
          bl[nt] = *(const s8v*)&Bsl[(wn + nt * 16 + l16) * 64 + kc * 32 + q4 * 8];
#pragma unroll
        for (int jt = 0; jt < 4; ++jt)
#pragma unroll
          for (int nt = 0; nt < 4; ++nt) {
            acc[jt][nt] = MFMA(ah[jt], bh[nt], acc[jt][nt]);
            acc[jt][nt] = MFMA(ah[jt], bl[nt], acc[jt][nt]);
            acc[jt][nt] = MFMA(al[jt], bh[nt], acc[jt][nt]);
          }
      } else {
#pragma unroll
        for (int jt = 0; jt < 4; ++jt)
#pragma unroll
          for (int nt = 0; nt < 4; ++nt) acc[jt][nt] = MFMA(ah[jt], bh[nt], acc[jt][nt]);
      }
    }
    __syncthreads();
  }

  // epilogue: affine + head-scatter  (C/D map: col=lane&15, row=q4*4+reg)
#pragma unroll
  for (int jt = 0; jt < 4; ++jt) {
#pragma unroll
    for (int nt = 0; nt < 4; ++nt) {
      int gcol = n0 + wn + nt * 16 + l16;
      int g = gcol >> hcShift, rem = gcol & hcMask;
      int hl = rem >> 6, d = rem & 63;
      int wcol = (g << 9) + ((h0 + hl) << 6) + d;
      float cs = colsum[wcol] * bfc;
#pragma unroll
      for (int r = 0; r < 4; ++r) {
        int grow = m0 + wm + jt * 16 + q4 * 4 + r;
        int i = grow >> 7, j = grow & 127;
        float val = acc[jt][nt][r] * af + cs;
        unsigned short hi = f2bf(val);
        if (g == 0) {
          size_t idx = (((size_t)hl * 128 + i) * 128 + j) * 64 + d;
          qhi[idx] = hi; qlo[idx] = f2bf(val - bf2f(hi));
        } else if (g == 1) {
          size_t idx = (((size_t)hl * 128 + i) * 128 + j) * 64 + d;  // k index = j
          k1hi[idx] = hi; k1lo[idx] = f2bf(val - bf2f(hi));
        } else if (g == 2) {
          size_t idx = (((size_t)hl * 128 + j) * 128 + i) * 64 + d;  // k2t[j][k=i][d]
          k2hi[idx] = hi; k2lo[idx] = f2bf(val - bf2f(hi));
        } else if (g == 3) {
          size_t idx = (((size_t)hl * 128 + i) * 64 + d) * 128 + j;  // v1T[i][d][k=j]
          v1T[idx] = hi;
        } else {
          size_t idx = (((size_t)hl * 128 + j) * 64 + d) * 128 + i;  // v2T[j][d][k=i]
          v2T[idx] = hi;
        }
      }
    }
  }
}

// ---------------------------------------------------------------------------
// 3) S1[j,k] = sum_d q[i,j,d]*k1[i,k,d] per (hl, i); hi/lo (3 MFMAs)
// ---------------------------------------------------------------------------
__global__ __launch_bounds__(256) void k_s1(
    const unsigned short* __restrict__ qhi, const unsigned short* __restrict__ qlo,
    const unsigned short* __restrict__ k1hi, const unsigned short* __restrict__ k1lo,
    float* __restrict__ S) {
  const int i = blockIdx.x, hl = blockIdx.y;
  const int t = threadIdx.x, lane = t & 63, wave = t >> 6;
  const int l16 = lane & 15, q4 = lane >> 4;
  const size_t base = ((size_t)hl * 128 + i) * 128 * 64;

  f4v acc[2][8];
#pragma unroll
  for (int a = 0; a < 2; ++a)
#pragma unroll
    for (int c = 0; c < 8; ++c) acc[a][c] = (f4v)0.f;

#pragma unroll
  for (int kc = 0; kc < 2; ++kc) {
    s8v ah[2], al[2];
#pragma unroll
    for (int jt = 0; jt < 2; ++jt) {
      size_t off = base + (size_t)(wave * 32 + jt * 16 + l16) * 64 + kc * 32 + q4 * 8;
      ah[jt] = *(const s8v*)(qhi + off);
      al[jt] = *(const s8v*)(qlo + off);
    }
#pragma unroll
    for (int kt = 0; kt < 8; ++kt) {
      size_t off = base + (size_t)(kt * 16 + l16) * 64 + kc * 32 + q4 * 8;
      s8v bh = *(const s8v*)(k1hi + off);
      s8v bl = *(const s8v*)(k1lo + off);
#pragma unroll
      for (int jt = 0; jt < 2; ++jt) {
        acc[jt][kt] = MFMA(ah[jt], bh, acc[jt][kt]);
        acc[jt][kt] = MFMA(ah[jt], bl, acc[jt][kt]);
        acc[jt][kt] = MFMA(al[jt], bh, acc[jt][kt]);
      }
    }
  }
  float* Sb = S + ((size_t)hl * 128 + i) * 128 * 128;
#pragma unroll
  for (int jt = 0; jt < 2; ++jt)
#pragma unroll
    for (int kt = 0; kt < 8; ++kt)
#pragma unroll
      for (int r = 0; r < 4; ++r) {
        int j = wave * 32 + jt * 16 + q4 * 4 + r;
        Sb[(size_t)j * 128 + kt * 16 + l16] = acc[jt][kt][r];
      }
}

// ---------------------------------------------------------------------------
// 4) S2[i,k] per (hl, j); add S1, scale, softmax over k, write attn bf16
// ---------------------------------------------------------------------------
__global__ __launch_bounds__(256) void k_s2(
    const unsigned short* __restrict__ qhi, const unsigned short* __restrict__ qlo,
    const unsigned short* __restrict__ k2hi, const unsigned short* __restrict__ k2lo,
    const float* __restrict__ S, unsigned short* __restrict__ attn) {
  const int j = blockIdx.x, hl = blockIdx.y;
  const int t = threadIdx.x, lane = t & 63, wave = t >> 6;
  const int l16 = lane & 15, q4 = lane >> 4;
  const size_t bbase = ((size_t)hl * 128 + j) * 128 * 64;  // k2t[hl][j]

  f4v acc[2][8];
#pragma unroll
  for (int a = 0; a < 2; ++a)
#pragma unroll
    for (int c = 0; c < 8; ++c) acc[a][c] = (f4v)0.f;

#pragma unroll
  for (int kc = 0; kc < 2; ++kc) {
    s8v ah[2], al[2];
#pragma unroll
    for (int it = 0; it < 2; ++it) {
      size_t off = (((size_t)hl * 128 + (wave * 32 + it * 16 + l16)) * 128 + j) * 64 +
                   kc * 32 + q4 * 8;
      ah[it] = *(const s8v*)(qhi + off);
      al[it] = *(const s8v*)(qlo + off);
    }
#pragma unroll
    for (int kt = 0; kt < 8; ++kt) {
      size_t off = bbase + (size_t)(kt * 16 + l16) * 64 + kc * 32 + q4 * 8;
      s8v bh = *(const s8v*)(k2hi + off);
      s8v bl = *(const s8v*)(k2lo + off);
#pragma unroll
      for (int it = 0; it < 2; ++it) {
        acc[it][kt] = MFMA(ah[it], bh, acc[it][kt]);
        acc[it][kt] = MFMA(ah[it], bl, acc[it][kt]);
        acc[it][kt] = MFMA(al[it], bh, acc[it][kt]);
      }
    }
  }

#pragma unroll
  for (int it = 0; it < 2; ++it) {
#pragma unroll
    for (int r = 0; r < 4; ++r) {
      int i = wave * 32 + it * 16 + q4 * 4 + r;
      const float* Srow = S + (((size_t)hl * 128 + i) * 128 + j) * 128;
      float tv[8];
      float m = -3.4e38f;
#pragma unroll
      for (int kt = 0; kt < 8; ++kt) {
        tv[kt] = 6.25f * (Srow[kt * 16 + l16] + acc[it][kt][r]);
        m = fmaxf(m, tv[kt]);
      }
#pragma unroll
      for (int d = 1; d <= 8; d <<= 1) m = fmaxf(m, __shfl_xor(m, d));
      float sum = 0.f;
#pragma unroll
      for (int kt = 0; kt < 8; ++kt) {
        tv[kt] = __expf(tv[kt] - m);
        sum += tv[kt];
      }
#pragma unroll
      for (int d = 1; d <= 8; d <<= 1) sum += __shfl_xor(sum, d);
      float rs = 1.f / sum;
      unsigned short* arow = attn + (((size_t)hl * 128 + i) * 128 + j) * 128;
#pragma unroll
      for (int kt = 0; kt < 8; ++kt) arow[kt * 16 + l16] = f2bf(tv[kt] * rs);
    }
  }
}

// ---------------------------------------------------------------------------
// 5) O1[j,d] = sum_k attn[i,j,k]*v1[i,k,d] per (hl, i); out1 fp32
// ---------------------------------------------------------------------------
__global__ __launch_bounds__(256) void k_av1(
    const unsigned short* __restrict__ attn, const unsigned short* __restrict__ v1T,
    float* __restrict__ out1) {
  const int i = blockIdx.x, hl = blockIdx.y;
  const int t = threadIdx.x, lane = t & 63, wave = t >> 6;
  const int l16 = lane & 15, q4 = lane >> 4;
  const size_t abase = ((size_t)hl * 128 + i) * 128 * 128;
  const size_t vbase = ((size_t)hl * 128 + i) * 64 * 128;

  f4v acc[2][4];
#pragma unroll
  for (int a = 0; a < 2; ++a)
#pragma unroll
    for (int c = 0; c < 4; ++c) acc[a][c] = (f4v)0.f;

#pragma unroll
  for (int kc = 0; kc < 4; ++kc) {
    s8v a[2], bfr[4];
#pragma unroll
    for (int jt = 0; jt < 2; ++jt)
      a[jt] = *(const s8v*)(attn + abase + (size_t)(wave * 32 + jt * 16 + l16) * 128 +
                            kc * 32 + q4 * 8);
#pragma unroll
    for (int dt = 0; dt < 4; ++dt)
      bfr[dt] = *(const s8v*)(v1T + vbase + (size_t)(dt * 16 + l16) * 128 + kc * 32 + q4 * 8);
#pragma unroll
    for (int jt = 0; jt < 2; ++jt)
#pragma unroll
      for (int dt = 0; dt < 4; ++dt) acc[jt][dt] = MFMA(a[jt], bfr[dt], acc[jt][dt]);
  }
  float* ob = out1 + ((size_t)hl * 128 + i) * 128 * 64;
#pragma unroll
  for (int jt = 0; jt < 2; ++jt)
#pragma unroll
    for (int dt = 0; dt < 4; ++dt)
#pragma unroll
      for (int r = 0; r < 4; ++r) {
        int j = wave * 32 + jt * 16 + q4 * 4 + r;
        ob[(size_t)j * 64 + dt * 16 + l16] = acc[jt][dt][r];
      }
}

// ---------------------------------------------------------------------------
// 6) O2[i,d] per (hl, j); add out1, dtype-branched final store
// ---------------------------------------------------------------------------
__global__ __launch_bounds__(256) void k_av2(
    const unsigned short* __restrict__ attn, const unsigned short* __restrict__ v2T,
    const float* __restrict__ out1, const int* __restrict__ flag,
    void* __restrict__ out, int b, int h0) {
  const int j = blockIdx.x, hl = blockIdx.y;
  const int t = threadIdx.x, lane = t & 63, wave = t >> 6;
  const int l16 = lane & 15, q4 = lane >> 4;
  const int fm = flag[0];
  const size_t vbase = ((size_t)hl * 128 + j) * 64 * 128;

  f4v acc[2][4];
#pragma unroll
  for (int a = 0; a < 2; ++a)
#pragma unroll
    for (int c = 0; c < 4; ++c) acc[a][c] = (f4v)0.f;

#pragma unroll
  for (int kc = 0; kc < 4; ++kc) {
    s8v a[2], bfr[4];
#pragma unroll
    for (int it = 0; it < 2; ++it)
      a[it] = *(const s8v*)(attn +
                            (((size_t)hl * 128 + (wave * 32 + it * 16 + l16)) * 128 + j) * 128 +
                            kc * 32 + q4 * 8);
#pragma unroll
    for (int dt = 0; dt < 4; ++dt)
      bfr[dt] = *(const s8v*)(v2T + vbase + (size_t)(dt * 16 + l16) * 128 + kc * 32 + q4 * 8);
#pragma unroll
    for (int it = 0; it < 2; ++it)
#pragma unroll
      for (int dt = 0; dt < 4; ++dt) acc[it][dt] = MFMA(a[it], bfr[dt], acc[it][dt]);
  }
#pragma unroll
  for (int it = 0; it < 2; ++it)
#pragma unroll
    for (int dt = 0; dt < 4; ++dt)
#pragma unroll
      for (int r = 0; r < 4; ++r) {
        int i = wave * 32 + it * 16 + q4 * 4 + r;
        int d = dt * 16 + l16;
        float o = acc[it][dt][r] + out1[(((size_t)hl * 128 + i) * 128 + j) * 64 + d];
        size_t oi = ((size_t)b * 16384 + i * 128 + j) * 512 + (h0 + hl) * 64 + d;
        if (fm) ((float*)out)[oi] = o;
        else    ((unsigned short*)out)[oi] = f2bf(o);
      }
}

// ---------------------------------------------------------------------------
extern "C" void kernel_launch(void* const* d_in, const int* in_sizes, int n_in,
                              void* d_out, int out_size, void* d_ws, size_t ws_size,
                              hipStream_t stream) {
  (void)in_sizes; (void)n_in; (void)out_size;
  const void* x = d_in[0];
  const void* w = d_in[1];

  // fixed-cost buffers: xhi/xlo per-b slice (16.78MB each), wT hi/lo, misc
  const size_t xslice = (size_t)16384 * 512;          // elements
  const size_t wTsz = (size_t)2560 * 512;
  const size_t fixed = xslice * 4 + wTsz * 4 + 2560 * 4 + 64;

  // chunk buffers: 32*TE bytes, TE = Hc*128*128*64 elements
  int Hc = 2;
  if (32 * ((size_t)8 * 1048576) + fixed <= ws_size) Hc = 8;
  else if (32 * ((size_t)4 * 1048576) + fixed <= ws_size) Hc = 4;
  const int hcShift = (Hc == 8) ? 9 : ((Hc == 4) ? 8 : 7);
  const size_t TE = (size_t)Hc * 1048576;

  char* p = (char*)d_ws;
  unsigned short* qhi = (unsigned short*)p;  p += TE * 2;
  unsigned short* qlo = (unsigned short*)p;  p += TE * 2;
  unsigned short* k1hi = (unsigned short*)p; p += TE * 2;
  unsigned short* k1lo = (unsigned short*)p; p += TE * 2;
  unsigned short* k2hi = (unsigned short*)p; p += TE * 2;
  unsigned short* k2lo = (unsigned short*)p; p += TE * 2;
  unsigned short* v1T = (unsigned short*)p;  p += TE * 2;
  unsigned short* v2T = (unsigned short*)p;  p += TE * 2;
  float* S = (float*)p;                      p += TE * 8;
  unsigned short* attn = (unsigned short*)p; p += TE * 4;
  float* out1 = (float*)p;                   p += TE * 4;
  unsigned short* xhi = (unsigned short*)p;  p += xslice * 2;
  unsigned short* xlo = (unsigned short*)p;  p += xslice * 2;
  unsigned short* wThi = (unsigned short*)p; p += wTsz * 2;
  unsigned short* wTlo = (unsigned short*)p; p += wTsz * 2;
  float* colsum = (float*)p;                 p += 2560 * 4;
  double* dstats = (double*)p;               p += 16;
  int* flag = (int*)p;                       p += 8;
  float* fstats = (float*)p;                 p += 8;

  hipMemsetAsync(dstats, 0, 24, stream);  // dstats[2] + flag
  k_probe<<<1, 256, 0, stream>>>((const unsigned short*)x, flag);
  k_red<<<512, 256, 0, stream>>>(x, flag, dstats);
  k_stats<<<1, 1, 0, stream>>>(dstats, fstats);
  k_colsum<<<10, 256, 0, stream>>>(w, flag, colsum);
  k_wt<<<dim3(40, 8), 256, 0, stream>>>(w, flag, wThi, wTlo);

  for (int b = 0; b < 4; ++b) {
    k_convx<<<4096, 256, 0, stream>>>(x, flag, xhi, xlo, b);
    for (int h0 = 0; h0 < 8; h0 += Hc) {
      k_gemm<<<dim3(128, (5 * Hc * 64) / 128), 256, 0, stream>>>(
          xhi, xlo, wThi, wTlo, colsum, fstats, flag,
          qhi, qlo, k1hi, k1lo, k2hi, k2lo, v1T, v2T, h0, hcShift);
      k_s1<<<dim3(128, Hc), 256, 0, stream>>>(qhi, qlo, k1hi, k1lo, S);
      k_s2<<<dim3(128, Hc), 256, 0, stream>>>(qhi, qlo, k2hi, k2lo, S, attn);
      k_av1<<<dim3(128, Hc), 256, 0, stream>>>(attn, v1T, out1);
      k_av2<<<dim3(128, Hc), 256, 0, stream>>>(attn, v2T, out1, flag, d_out, b, h0);
    }
  }
}

// Round 3
// 1648.918 us; speedup vs baseline: 1.0551x; 1.0551x over previous
//
#include <hip/hip_runtime.h>
#include <stdint.h>

// ---------------------------------------------------------------------------
// FloydBlock2: global-norm -> QKV GEMM -> pivotal attention (row+col streams)
// B=4, N=128, C=512, H=8, D=64, SCALE=6.25
// Dtype-adaptive (probe): fp32 or bf16 I/O. GEMM uses hi/lo bf16 splits.
// R3: XOR bank-swizzle on GEMM LDS tiles (16-way -> 2-way); out1 bf16.
// ---------------------------------------------------------------------------

typedef __attribute__((ext_vector_type(8))) short s8v;   // 8 x bf16 (4 VGPRs)
typedef __attribute__((ext_vector_type(4))) float f4v;   // MFMA accumulator

#define MFMA(a, b, c) __builtin_amdgcn_mfma_f32_16x16x32_bf16((a), (b), (c), 0, 0, 0)

__device__ __forceinline__ float bf2f(unsigned short u) {
  union { unsigned int i; float f; } v; v.i = ((unsigned int)u) << 16; return v.f;
}
__device__ __forceinline__ unsigned short f2bf(float f) {
  union { float f; unsigned int i; } v; v.f = f;
  unsigned int i = v.i;
  return (unsigned short)((i + 0x7fffu + ((i >> 16) & 1u)) >> 16);  // RNE
}

__device__ __forceinline__ void async_copy16(const void* g, void* l) {
  __builtin_amdgcn_global_load_lds(
      (const __attribute__((address_space(1))) unsigned int*)(uintptr_t)g,
      (__attribute__((address_space(3))) unsigned int*)(uintptr_t)l,
      16, 0, 0);
}

// ---------------------------------------------------------------------------
// 0) dtype probe
// ---------------------------------------------------------------------------
__global__ __launch_bounds__(256) void k_probe(const unsigned short* __restrict__ x,
                                               int* __restrict__ flag) {
  uint4 v = ((const uint4*)x)[threadIdx.x];
  unsigned int uu[4] = {v.x, v.y, v.z, v.w};
  int bad = 0;
#pragma unroll
  for (int u = 0; u < 4; ++u) {
    float a = bf2f((unsigned short)(uu[u] & 0xffffu));
    float b = bf2f((unsigned short)(uu[u] >> 16));
    if (!(fabsf(a) <= 1e4f)) bad = 1;
    if (!(fabsf(b) <= 1e4f)) bad = 1;
  }
  if (bad) atomicOr(flag, 1);
}

// ---------------------------------------------------------------------------
// 1) Global sum / sumsq over raw x
// ---------------------------------------------------------------------------
__global__ __launch_bounds__(256) void k_red(const void* __restrict__ xraw,
                                             const int* __restrict__ flag,
                                             double* __restrict__ dstats) {
  __shared__ float red[8];
  const int fm = flag[0];
  int t = threadIdx.x;
  size_t gid = (size_t)blockIdx.x * 256 + t;
  float s = 0.f, ss = 0.f;
  if (fm) {
    const float4* pf = (const float4*)xraw;
#pragma unroll 4
    for (int it = 0; it < 32; ++it) {
      size_t idx = gid + (size_t)it * 131072;
      float4 u1 = pf[2 * idx], u2 = pf[2 * idx + 1];
      float vals[8] = {u1.x, u1.y, u1.z, u1.w, u2.x, u2.y, u2.z, u2.w};
#pragma unroll
      for (int u = 0; u < 8; ++u) { s += vals[u]; ss += vals[u] * vals[u]; }
    }
  } else {
    const uint4* p = (const uint4*)xraw;
#pragma unroll 4
    for (int it = 0; it < 32; ++it) {
      uint4 v = p[gid + (size_t)it * 131072];
      unsigned int uu[4] = {v.x, v.y, v.z, v.w};
#pragma unroll
      for (int u = 0; u < 4; ++u) {
        float a = bf2f((unsigned short)(uu[u] & 0xffffu));
        float b = bf2f((unsigned short)(uu[u] >> 16));
        s += a + b;
        ss += a * a + b * b;
      }
    }
  }
#pragma unroll
  for (int d = 32; d >= 1; d >>= 1) {
    s += __shfl_down(s, d);
    ss += __shfl_down(ss, d);
  }
  int lane = t & 63, wave = t >> 6;
  if (lane == 0) { red[wave] = s; red[4 + wave] = ss; }
  __syncthreads();
  if (t == 0) {
    atomicAdd(&dstats[0], (double)(red[0] + red[1] + red[2] + red[3]));
    atomicAdd(&dstats[1], (double)(red[4] + red[5] + red[6] + red[7]));
  }
}

__global__ void k_stats(const double* __restrict__ dstats, float* __restrict__ fstats) {
  double M = 33554432.0;
  double mean = dstats[0] / M;
  double var = (dstats[1] - dstats[0] * dstats[0] / M) / (M - 1.0);  // ddof=1
  double istd = 1.0 / sqrt(var);
  fstats[0] = (float)istd;
  fstats[1] = (float)(-mean * istd);
}

__global__ __launch_bounds__(256) void k_colsum(const void* __restrict__ wraw,
                                                const int* __restrict__ flag,
                                                float* __restrict__ colsum) {
  const int fm = flag[0];
  int c = blockIdx.x * 256 + threadIdx.x;
  if (c >= 2560) return;
  float s = 0.f;
  if (fm) {
    const float* w = (const float*)wraw;
    for (int r = 0; r < 512; ++r) s += w[(size_t)r * 2560 + c];
  } else {
    const unsigned short* w = (const unsigned short*)wraw;
    for (int r = 0; r < 512; ++r) s += bf2f(w[(size_t)r * 2560 + c]);
  }
  colsum[c] = s;
}

// wT hi/lo [n][k] = split(w[k][n])  (2560 x 512)
__global__ __launch_bounds__(256) void k_wt(const void* __restrict__ wraw,
                                            const int* __restrict__ flag,
                                            unsigned short* __restrict__ wThi,
                                            unsigned short* __restrict__ wTlo) {
  __shared__ float tile[64][65];
  const int fm = flag[0];
  int n0 = blockIdx.x * 64, r0 = blockIdx.y * 64;
#pragma unroll
  for (int rep = 0; rep < 16; ++rep) {
    int idx = rep * 256 + threadIdx.x;
    int r = idx >> 6, n = idx & 63;
    float v;
    if (fm) v = ((const float*)wraw)[(size_t)(r0 + r) * 2560 + n0 + n];
    else    v = bf2f(((const unsigned short*)wraw)[(size_t)(r0 + r) * 2560 + n0 + n]);
    tile[r][n] = v;
  }
  __syncthreads();
#pragma unroll
  for (int rep = 0; rep < 16; ++rep) {
    int idx = rep * 256 + threadIdx.x;
    int n = idx >> 6, r = idx & 63;
    float v = tile[r][n];
    unsigned short hi = f2bf(v);
    size_t o = (size_t)(n0 + n) * 512 + r0 + r;
    wThi[o] = hi;
    wTlo[o] = f2bf(v - bf2f(hi));
  }
}

// per-b slice conversion: x[b] -> xhi/xlo bf16 [16384][512]
__global__ __launch_bounds__(256) void k_convx(const void* __restrict__ xraw,
                                               const int* __restrict__ flag,
                                               unsigned short* __restrict__ xhi,
                                               unsigned short* __restrict__ xlo,
                                               int b) {
  const int fm = flag[0];
  size_t e0 = ((size_t)blockIdx.x * 256 + threadIdx.x) * 8;
  size_t g0 = (size_t)b * 8388608 + e0;
  float vals[8];
  if (fm) {
    const float4* pf = (const float4*)xraw;
    float4 u1 = pf[g0 / 4], u2 = pf[g0 / 4 + 1];
    vals[0] = u1.x; vals[1] = u1.y; vals[2] = u1.z; vals[3] = u1.w;
    vals[4] = u2.x; vals[5] = u2.y; vals[6] = u2.z; vals[7] = u2.w;
  } else {
    uint4 v = ((const uint4*)xraw)[g0 / 8];
    unsigned int uu[4] = {v.x, v.y, v.z, v.w};
#pragma unroll
    for (int u = 0; u < 4; ++u) {
      vals[2 * u] = bf2f((unsigned short)(uu[u] & 0xffffu));
      vals[2 * u + 1] = bf2f((unsigned short)(uu[u] >> 16));
    }
  }
  unsigned short h[8], l[8];
#pragma unroll
  for (int u = 0; u < 8; ++u) {
    h[u] = f2bf(vals[u]);
    l[u] = f2bf(vals[u] - bf2f(h[u]));
  }
  *(uint4*)(xhi + e0) = *(const uint4*)h;
  *(uint4*)(xlo + e0) = *(const uint4*)l;
}

// ---------------------------------------------------------------------------
// 2) QKV GEMM, 128x128x64 tiles, hi/lo 3-term MFMA, XOR bank-swizzled LDS.
//    LDS[row][c] holds global[row][c ^ (row&7)] (16B chunks, 8 per 64-el row).
// ---------------------------------------------------------------------------
__global__ __launch_bounds__(256) void k_gemm(
    const unsigned short* __restrict__ xhi, const unsigned short* __restrict__ xlo,
    const unsigned short* __restrict__ wThi, const unsigned short* __restrict__ wTlo,
    const float* __restrict__ colsum, const float* __restrict__ fstats,
    const int* __restrict__ flag,
    unsigned short* __restrict__ qhi, unsigned short* __restrict__ qlo,
    unsigned short* __restrict__ k1hi, unsigned short* __restrict__ k1lo,
    unsigned short* __restrict__ k2hi, unsigned short* __restrict__ k2lo,
    unsigned short* __restrict__ v1T, unsigned short* __restrict__ v2T,
    int h0, int hcShift) {
  __shared__ __align__(16) unsigned short Ash[128 * 64];
  __shared__ __align__(16) unsigned short Asl[128 * 64];
  __shared__ __align__(16) unsigned short Bsh[128 * 64];
  __shared__ __align__(16) unsigned short Bsl[128 * 64];
  const int fm = flag[0];
  const int t = threadIdx.x;
  const int m0 = blockIdx.x * 128;
  const int n0 = blockIdx.y * 128;
  const int hcMask = (1 << hcShift) - 1;

  const int lane = t & 63, wave = t >> 6;
  const int wm = (wave & 1) * 64, wn = (wave >> 1) * 64;
  const int l16 = lane & 15, q4 = lane >> 4;
  const int srow = t >> 3;                               // staging row 0..31
  const int scol = (((t & 7) ^ ((t >> 3) & 7)) * 8);     // swizzled source chunk
  const int rsw = l16 & 7;                               // read-side swizzle key

  const float af = fstats[0], bfc = fstats[1];
  const unsigned short* xh = xhi + (size_t)m0 * 512;
  const unsigned short* xl = xlo + (size_t)m0 * 512;

  // precompute B-side source cols for the 4 staged rows
  int wcolr[4];
#pragma unroll
  for (int r = 0; r < 4; ++r) {
    int ncol = n0 + r * 32 + srow;
    int g = ncol >> hcShift, rem = ncol & hcMask;
    wcolr[r] = (g << 9) + ((h0 + (rem >> 6)) << 6) + (rem & 63);
  }

  f4v acc[4][4];
#pragma unroll
  for (int a = 0; a < 4; ++a)
#pragma unroll
    for (int c = 0; c < 4; ++c) acc[a][c] = (f4v)0.f;

  for (int k0 = 0; k0 < 512; k0 += 64) {
#pragma unroll
    for (int r = 0; r < 4; ++r) {
      int row = r * 32 + srow;
      async_copy16(xh + (size_t)row * 512 + k0 + scol, (char*)Ash + (r * 256 + t) * 16);
    }
#pragma unroll
    for (int r = 0; r < 4; ++r)
      async_copy16(wThi + (size_t)wcolr[r] * 512 + k0 + scol, (char*)Bsh + (r * 256 + t) * 16);
    if (fm) {
#pragma unroll
      for (int r = 0; r < 4; ++r) {
        int row = r * 32 + srow;
        async_copy16(xl + (size_t)row * 512 + k0 + scol, (char*)Asl + (r * 256 + t) * 16);
      }
#pragma unroll
      for (int r = 0; r < 4; ++r)
        async_copy16(wTlo + (size_t)wcolr[r] * 512 + k0 + scol, (char*)Bsl + (r * 256 + t) * 16);
    }
    __syncthreads();
#pragma unroll
    for (int kc = 0; kc < 2; ++kc) {
      const int swoff = ((kc * 4 + q4) ^ rsw) * 8;   // swizzled element offset in row
      s8v ah[4], bh[4];
#pragma unroll
      for (int jt = 0; jt < 4; ++jt)
        ah[jt] = *(const s8v*)&Ash[(wm + jt * 16 + l16) * 64 + swoff];
#pragma unroll
      for (int nt = 0; nt < 4; ++nt)
        bh[nt] = *(const s8v*)&Bsh[(wn + nt * 16 + l16) * 64 + swoff];
      if (fm) {
        s8v al[4], bl[4];
#pragma unroll
        for (int jt = 0; jt < 4; ++jt)
          al[jt] = *(const s8v*)&Asl[(wm + jt * 16 + l16) * 64 + swoff];
#pragma unroll
        for (int nt = 0; nt < 4; ++nt)
          bl[nt] = *(const s8v*)&Bsl[(wn + nt * 16 + l16) * 64 + swoff];
#pragma unroll
        for (int jt = 0; jt < 4; ++jt)
#pragma unroll
          for (int nt = 0; nt < 4; ++nt) {
            acc[jt][nt] = MFMA(ah[jt], bh[nt], acc[jt][nt]);
            acc[jt][nt] = MFMA(ah[jt], bl[nt], acc[jt][nt]);
            acc[jt][nt] = MFMA(al[jt], bh[nt], acc[jt][nt]);
          }
      } else {
#pragma unroll
        for (int jt = 0; jt < 4; ++jt)
#pragma unroll
          for (int nt = 0; nt < 4; ++nt) acc[jt][nt] = MFMA(ah[jt], bh[nt], acc[jt][nt]);
      }
    }
    __syncthreads();
  }

  // epilogue: affine + head-scatter  (C/D map: col=lane&15, row=q4*4+reg)
#pragma unroll
  for (int jt = 0; jt < 4; ++jt) {
#pragma unroll
    for (int nt = 0; nt < 4; ++nt) {
      int gcol = n0 + wn + nt * 16 + l16;
      int g = gcol >> hcShift, rem = gcol & hcMask;
      int hl = rem >> 6, d = rem & 63;
      int wcol = (g << 9) + ((h0 + hl) << 6) + d;
      float cs = colsum[wcol] * bfc;
#pragma unroll
      for (int r = 0; r < 4; ++r) {
        int grow = m0 + wm + jt * 16 + q4 * 4 + r;
        int i = grow >> 7, j = grow & 127;
        float val = acc[jt][nt][r] * af + cs;
        unsigned short hi = f2bf(val);
        if (g == 0) {
          size_t idx = (((size_t)hl * 128 + i) * 128 + j) * 64 + d;
          qhi[idx] = hi; qlo[idx] = f2bf(val - bf2f(hi));
        } else if (g == 1) {
          size_t idx = (((size_t)hl * 128 + i) * 128 + j) * 64 + d;
          k1hi[idx] = hi; k1lo[idx] = f2bf(val - bf2f(hi));
        } else if (g == 2) {
          size_t idx = (((size_t)hl * 128 + j) * 128 + i) * 64 + d;
          k2hi[idx] = hi; k2lo[idx] = f2bf(val - bf2f(hi));
        } else if (g == 3) {
          size_t idx = (((size_t)hl * 128 + i) * 64 + d) * 128 + j;
          v1T[idx] = hi;
        } else {
          size_t idx = (((size_t)hl * 128 + j) * 64 + d) * 128 + i;
          v2T[idx] = hi;
        }
      }
    }
  }
}

// ---------------------------------------------------------------------------
// 3) S1[j,k] = sum_d q[i,j,d]*k1[i,k,d] per (hl, i)
// ---------------------------------------------------------------------------
__global__ __launch_bounds__(256) void k_s1(
    const unsigned short* __restrict__ qhi, const unsigned short* __restrict__ qlo,
    const unsigned short* __restrict__ k1hi, const unsigned short* __restrict__ k1lo,
    float* __restrict__ S) {
  const int i = blockIdx.x, hl = blockIdx.y;
  const int t = threadIdx.x, lane = t & 63, wave = t >> 6;
  const int l16 = lane & 15, q4 = lane >> 4;
  const size_t base = ((size_t)hl * 128 + i) * 128 * 64;

  f4v acc[2][8];
#pragma unroll
  for (int a = 0; a < 2; ++a)
#pragma unroll
    for (int c = 0; c < 8; ++c) acc[a][c] = (f4v)0.f;

#pragma unroll
  for (int kc = 0; kc < 2; ++kc) {
    s8v ah[2], al[2];
#pragma unroll
    for (int jt = 0; jt < 2; ++jt) {
      size_t off = base + (size_t)(wave * 32 + jt * 16 + l16) * 64 + kc * 32 + q4 * 8;
      ah[jt] = *(const s8v*)(qhi + off);
      al[jt] = *(const s8v*)(qlo + off);
    }
#pragma unroll
    for (int kt = 0; kt < 8; ++kt) {
      size_t off = base + (size_t)(kt * 16 + l16) * 64 + kc * 32 + q4 * 8;
      s8v bh = *(const s8v*)(k1hi + off);
      s8v bl = *(const s8v*)(k1lo + off);
#pragma unroll
      for (int jt = 0; jt < 2; ++jt) {
        acc[jt][kt] = MFMA(ah[jt], bh, acc[jt][kt]);
        acc[jt][kt] = MFMA(ah[jt], bl, acc[jt][kt]);
        acc[jt][kt] = MFMA(al[jt], bh, acc[jt][kt]);
      }
    }
  }
  float* Sb = S + ((size_t)hl * 128 + i) * 128 * 128;
#pragma unroll
  for (int jt = 0; jt < 2; ++jt)
#pragma unroll
    for (int kt = 0; kt < 8; ++kt)
#pragma unroll
      for (int r = 0; r < 4; ++r) {
        int j = wave * 32 + jt * 16 + q4 * 4 + r;
        Sb[(size_t)j * 128 + kt * 16 + l16] = acc[jt][kt][r];
      }
}

// ---------------------------------------------------------------------------
// 4) S2[i,k] per (hl, j); add S1, scale, softmax over k, write attn bf16
// ---------------------------------------------------------------------------
__global__ __launch_bounds__(256) void k_s2(
    const unsigned short* __restrict__ qhi, const unsigned short* __restrict__ qlo,
    const unsigned short* __restrict__ k2hi, const unsigned short* __restrict__ k2lo,
    const float* __restrict__ S, unsigned short* __restrict__ attn) {
  const int j = blockIdx.x, hl = blockIdx.y;
  const int t = threadIdx.x, lane = t & 63, wave = t >> 6;
  const int l16 = lane & 15, q4 = lane >> 4;
  const size_t bbase = ((size_t)hl * 128 + j) * 128 * 64;

  f4v acc[2][8];
#pragma unroll
  for (int a = 0; a < 2; ++a)
#pragma unroll
    for (int c = 0; c < 8; ++c) acc[a][c] = (f4v)0.f;

#pragma unroll
  for (int kc = 0; kc < 2; ++kc) {
    s8v ah[2], al[2];
#pragma unroll
    for (int it = 0; it < 2; ++it) {
      size_t off = (((size_t)hl * 128 + (wave * 32 + it * 16 + l16)) * 128 + j) * 64 +
                   kc * 32 + q4 * 8;
      ah[it] = *(const s8v*)(qhi + off);
      al[it] = *(const s8v*)(qlo + off);
    }
#pragma unroll
    for (int kt = 0; kt < 8; ++kt) {
      size_t off = bbase + (size_t)(kt * 16 + l16) * 64 + kc * 32 + q4 * 8;
      s8v bh = *(const s8v*)(k2hi + off);
      s8v bl = *(const s8v*)(k2lo + off);
#pragma unroll
      for (int it = 0; it < 2; ++it) {
        acc[it][kt] = MFMA(ah[it], bh, acc[it][kt]);
        acc[it][kt] = MFMA(ah[it], bl, acc[it][kt]);
        acc[it][kt] = MFMA(al[it], bh, acc[it][kt]);
      }
    }
  }

#pragma unroll
  for (int it = 0; it < 2; ++it) {
#pragma unroll
    for (int r = 0; r < 4; ++r) {
      int i = wave * 32 + it * 16 + q4 * 4 + r;
      const float* Srow = S + (((size_t)hl * 128 + i) * 128 + j) * 128;
      float tv[8];
      float m = -3.4e38f;
#pragma unroll
      for (int kt = 0; kt < 8; ++kt) {
        tv[kt] = 6.25f * (Srow[kt * 16 + l16] + acc[it][kt][r]);
        m = fmaxf(m, tv[kt]);
      }
#pragma unroll
      for (int d = 1; d <= 8; d <<= 1) m = fmaxf(m, __shfl_xor(m, d));
      float sum = 0.f;
#pragma unroll
      for (int kt = 0; kt < 8; ++kt) {
        tv[kt] = __expf(tv[kt] - m);
        sum += tv[kt];
      }
#pragma unroll
      for (int d = 1; d <= 8; d <<= 1) sum += __shfl_xor(sum, d);
      float rs = 1.f / sum;
      unsigned short* arow = attn + (((size_t)hl * 128 + i) * 128 + j) * 128;
#pragma unroll
      for (int kt = 0; kt < 8; ++kt) arow[kt * 16 + l16] = f2bf(tv[kt] * rs);
    }
  }
}

// ---------------------------------------------------------------------------
// 5) O1[j,d] = sum_k attn[i,j,k]*v1[i,k,d] per (hl, i); out1 bf16
// ---------------------------------------------------------------------------
__global__ __launch_bounds__(256) void k_av1(
    const unsigned short* __restrict__ attn, const unsigned short* __restrict__ v1T,
    unsigned short* __restrict__ out1) {
  const int i = blockIdx.x, hl = blockIdx.y;
  const int t = threadIdx.x, lane = t & 63, wave = t >> 6;
  const int l16 = lane & 15, q4 = lane >> 4;
  const size_t abase = ((size_t)hl * 128 + i) * 128 * 128;
  const size_t vbase = ((size_t)hl * 128 + i) * 64 * 128;

  f4v acc[2][4];
#pragma unroll
  for (int a = 0; a < 2; ++a)
#pragma unroll
    for (int c = 0; c < 4; ++c) acc[a][c] = (f4v)0.f;

#pragma unroll
  for (int kc = 0; kc < 4; ++kc) {
    s8v a[2], bfr[4];
#pragma unroll
    for (int jt = 0; jt < 2; ++jt)
      a[jt] = *(const s8v*)(attn + abase + (size_t)(wave * 32 + jt * 16 + l16) * 128 +
                            kc * 32 + q4 * 8);
#pragma unroll
    for (int dt = 0; dt < 4; ++dt)
      bfr[dt] = *(const s8v*)(v1T + vbase + (size_t)(dt * 16 + l16) * 128 + kc * 32 + q4 * 8);
#pragma unroll
    for (int jt = 0; jt < 2; ++jt)
#pragma unroll
      for (int dt = 0; dt < 4; ++dt) acc[jt][dt] = MFMA(a[jt], bfr[dt], acc[jt][dt]);
  }
  unsigned short* ob = out1 + ((size_t)hl * 128 + i) * 128 * 64;
#pragma unroll
  for (int jt = 0; jt < 2; ++jt)
#pragma unroll
    for (int dt = 0; dt < 4; ++dt)
#pragma unroll
      for (int r = 0; r < 4; ++r) {
        int j = wave * 32 + jt * 16 + q4 * 4 + r;
        ob[(size_t)j * 64 + dt * 16 + l16] = f2bf(acc[jt][dt][r]);
      }
}

// ---------------------------------------------------------------------------
// 6) O2[i,d] per (hl, j); add out1, dtype-branched final store
// ---------------------------------------------------------------------------
__global__ __launch_bounds__(256) void k_av2(
    const unsigned short* __restrict__ attn, const unsigned short* __restrict__ v2T,
    const unsigned short* __restrict__ out1, const int* __restrict__ flag,
    void* __restrict__ out, int b, int h0) {
  const int j = blockIdx.x, hl = blockIdx.y;
  const int t = threadIdx.x, lane = t & 63, wave = t >> 6;
  const int l16 = lane & 15, q4 = lane >> 4;
  const int fm = flag[0];
  const size_t vbase = ((size_t)hl * 128 + j) * 64 * 128;

  f4v acc[2][4];
#pragma unroll
  for (int a = 0; a < 2; ++a)
#pragma unroll
    for (int c = 0; c < 4; ++c) acc[a][c] = (f4v)0.f;

#pragma unroll
  for (int kc = 0; kc < 4; ++kc) {
    s8v a[2], bfr[4];
#pragma unroll
    for (int it = 0; it < 2; ++it)
      a[it] = *(const s8v*)(attn +
                            (((size_t)hl * 128 + (wave * 32 + it * 16 + l16)) * 128 + j) * 128 +
                            kc * 32 + q4 * 8);
#pragma unroll
    for (int dt = 0; dt < 4; ++dt)
      bfr[dt] = *(const s8v*)(v2T + vbase + (size_t)(dt * 16 + l16) * 128 + kc * 32 + q4 * 8);
#pragma unroll
    for (int it = 0; it < 2; ++it)
#pragma unroll
      for (int dt = 0; dt < 4; ++dt) acc[it][dt] = MFMA(a[it], bfr[dt], acc[it][dt]);
  }
#pragma unroll
  for (int it = 0; it < 2; ++it)
#pragma unroll
    for (int dt = 0; dt < 4; ++dt)
#pragma unroll
      for (int r = 0; r < 4; ++r) {
        int i = wave * 32 + it * 16 + q4 * 4 + r;
        int d = dt * 16 + l16;
        float o = acc[it][dt][r] + bf2f(out1[(((size_t)hl * 128 + i) * 128 + j) * 64 + d]);
        size_t oi = ((size_t)b * 16384 + i * 128 + j) * 512 + (h0 + hl) * 64 + d;
        if (fm) ((float*)out)[oi] = o;
        else    ((unsigned short*)out)[oi] = f2bf(o);
      }
}

// ---------------------------------------------------------------------------
extern "C" void kernel_launch(void* const* d_in, const int* in_sizes, int n_in,
                              void* d_out, int out_size, void* d_ws, size_t ws_size,
                              hipStream_t stream) {
  (void)in_sizes; (void)n_in; (void)out_size;
  const void* x = d_in[0];
  const void* w = d_in[1];

  const size_t xslice = (size_t)16384 * 512;
  const size_t wTsz = (size_t)2560 * 512;
  const size_t fixed = xslice * 4 + wTsz * 4 + 2560 * 4 + 64;

  int Hc = 2;
  if (30 * ((size_t)8 * 1048576) + fixed <= ws_size) Hc = 8;
  else if (30 * ((size_t)4 * 1048576) + fixed <= ws_size) Hc = 4;
  const int hcShift = (Hc == 8) ? 9 : ((Hc == 4) ? 8 : 7);
  const size_t TE = (size_t)Hc * 1048576;

  char* p = (char*)d_ws;
  unsigned short* qhi = (unsigned short*)p;  p += TE * 2;
  unsigned short* qlo = (unsigned short*)p;  p += TE * 2;
  unsigned short* k1hi = (unsigned short*)p; p += TE * 2;
  unsigned short* k1lo = (unsigned short*)p; p += TE * 2;
  unsigned short* k2hi = (unsigned short*)p; p += TE * 2;
  unsigned short* k2lo = (unsigned short*)p; p += TE * 2;
  unsigned short* v1T = (unsigned short*)p;  p += TE * 2;
  unsigned short* v2T = (unsigned short*)p;  p += TE * 2;
  float* S = (float*)p;                      p += TE * 8;
  unsigned short* attn = (unsigned short*)p; p += TE * 4;
  unsigned short* out1 = (unsigned short*)p; p += TE * 2;
  unsigned short* xhi = (unsigned short*)p;  p += xslice * 2;
  unsigned short* xlo = (unsigned short*)p;  p += xslice * 2;
  unsigned short* wThi = (unsigned short*)p; p += wTsz * 2;
  unsigned short* wTlo = (unsigned short*)p; p += wTsz * 2;
  float* colsum = (float*)p;                 p += 2560 * 4;
  double* dstats = (double*)p;               p += 16;
  int* flag = (int*)p;                       p += 8;
  float* fstats = (float*)p;                 p += 8;

  hipMemsetAsync(dstats, 0, 24, stream);  // dstats[2] + flag
  k_probe<<<1, 256, 0, stream>>>((const unsigned short*)x, flag);
  k_red<<<512, 256, 0, stream>>>(x, flag, dstats);
  k_stats<<<1, 1, 0, stream>>>(dstats, fstats);
  k_colsum<<<10, 256, 0, stream>>>(w, flag, colsum);
  k_wt<<<dim3(40, 8), 256, 0, stream>>>(w, flag, wThi, wTlo);

  for (int b = 0; b < 4; ++b) {
    k_convx<<<4096, 256, 0, stream>>>(x, flag, xhi, xlo, b);
    for (int h0 = 0; h0 < 8; h0 += Hc) {
      k_gemm<<<dim3(128, (5 * Hc * 64) / 128), 256, 0, stream>>>(
          xhi, xlo, wThi, wTlo, colsum, fstats, flag,
          qhi, qlo, k1hi, k1lo, k2hi, k2lo, v1T, v2T, h0, hcShift);
      k_s1<<<dim3(128, Hc), 256, 0, stream>>>(qhi, qlo, k1hi, k1lo, S);
      k_s2<<<dim3(128, Hc), 256, 0, stream>>>(qhi, qlo, k2hi, k2lo, S, attn);
      k_av1<<<dim3(128, Hc), 256, 0, stream>>>(attn, v1T, out1);
      k_av2<<<dim3(128, Hc), 256, 0, stream>>>(attn, v2T, out1, flag, d_out, b, h0);
    }
  }
}